// Round 7
// baseline (478.173 us; speedup 1.0000x reference)
//
#include <hip/hip_runtime.h>
#include <hip/hip_fp16.h>

typedef __attribute__((ext_vector_type(8))) short short8;
typedef __attribute__((ext_vector_type(4))) short short4v;
typedef __attribute__((ext_vector_type(4))) float floatx4;
typedef _Float16 half8 __attribute__((ext_vector_type(8)));
typedef _Float16 half2v __attribute__((ext_vector_type(2)));

static __device__ __forceinline__ short f2h(float f) {
    _Float16 h = (_Float16)f;
    return __builtin_bit_cast(short, h);
}

static __device__ __forceinline__ int pk2(float a, float b) {
    return __builtin_bit_cast(int, __builtin_amdgcn_cvt_pkrtz(a, b));
}

static __device__ __forceinline__ floatx4 mfma16(short8 a, short8 b, floatx4 c) {
    return __builtin_amdgcn_mfma_f32_16x16x32_f16(__builtin_bit_cast(half8, a),
                                                  __builtin_bit_cast(half8, b), c, 0, 0, 0);
}

static __device__ __forceinline__ void async16(const void* g, void* l) {
    __builtin_amdgcn_global_load_lds((const __attribute__((address_space(1))) void*)g,
                                     (__attribute__((address_space(3))) void*)l, 16, 0, 0);
}

// ---------------------------------------------------------------- LayerNorm -> fp16
__global__ __launch_bounds__(256) void ln_kernel(const float* __restrict__ x,
                                                 const float* __restrict__ gamma,
                                                 const float* __restrict__ beta,
                                                 short* __restrict__ xh) {
    __shared__ float red[8];
    const int row = blockIdx.x, tid = threadIdx.x;
    const int w = tid >> 6, lane = tid & 63;
    const float4 v = ((const float4*)(x + (size_t)row * 1024))[tid];
    float s = v.x + v.y + v.z + v.w;
    float ss = v.x * v.x + v.y * v.y + v.z * v.z + v.w * v.w;
#pragma unroll
    for (int off = 32; off; off >>= 1) {
        s += __shfl_xor(s, off);
        ss += __shfl_xor(ss, off);
    }
    if (lane == 0) { red[w] = s; red[4 + w] = ss; }
    __syncthreads();
    s = red[0] + red[1] + red[2] + red[3];
    ss = red[4] + red[5] + red[6] + red[7];
    const float mu = s * (1.f / 1024.f);
    const float rs = rsqrtf(ss * (1.f / 1024.f) - mu * mu + 1e-5f);
    const float4 g = ((const float4*)gamma)[tid];
    const float4 bt = ((const float4*)beta)[tid];
    short4v ph;
    ph[0] = f2h((v.x - mu) * rs * g.x + bt.x);
    ph[1] = f2h((v.y - mu) * rs * g.y + bt.y);
    ph[2] = f2h((v.z - mu) * rs * g.z + bt.z);
    ph[3] = f2h((v.w - mu) * rs * g.w + bt.w);
    *(short4v*)(xh + (size_t)row * 1024 + tid * 4) = ph;
}

// ------------------------------------------------- transpose + cast fp32 -> fp16
__global__ void tcast_h(const float* __restrict__ in, short* __restrict__ out, int R, int C) {
    __shared__ float t[32][33];
    const int bx = blockIdx.x * 32, by = blockIdx.y * 32;
    const int tx = threadIdx.x, ty = threadIdx.y;
#pragma unroll
    for (int i = 0; i < 32; i += 8) t[ty + i][tx] = in[(size_t)(by + ty + i) * C + bx + tx];
    __syncthreads();
#pragma unroll
    for (int i = 0; i < 32; i += 8) out[(size_t)(bx + ty + i) * R + by + tx] = f2h(t[tx][ty + i]);
}

// ---------------------------------------------------------------- QKV GEMM (plain fp16)
// (byte-identical to the R6 passing version)
__global__ __launch_bounds__(256, 2) void gemm_qkv(const short* __restrict__ A,
                                                   const short* __restrict__ BT,
                                                   short* __restrict__ Qd, short* __restrict__ Kd,
                                                   short* __restrict__ VTb) {
    extern __shared__ __align__(16) short pool[];  // 34816 B
    short* sA = pool;          // [128][32]
    short* sB = pool + 4096;   // [128][32]
    short* sOut = pool;        // alias after barrier: [128][136]

    const int tid = threadIdx.x;
    const int w = tid >> 6, lane = tid & 63, quad = lane >> 4, l15 = lane & 15;
    const int wm = w >> 1, wn = w & 1;
    const int m0 = blockIdx.y * 128, n0 = blockIdx.x * 128;

    floatx4 acc[4][4];
#pragma unroll
    for (int i = 0; i < 4; i++)
#pragma unroll
        for (int j = 0; j < 4; j++) acc[i][j] = (floatx4){0.f, 0.f, 0.f, 0.f};

    for (int k0 = 0; k0 < 1024; k0 += 32) {
        __syncthreads();
#pragma unroll
        for (int i = 0; i < 2; ++i) {
            int c = i * 256 + tid;
            int r = c >> 2, kc = (c & 3) << 3;
            async16(A + (size_t)(m0 + r) * 1024 + k0 + kc, (char*)sA + c * 16);
            async16(BT + (size_t)(n0 + r) * 1024 + k0 + kc, (char*)sB + c * 16);
        }
        __syncthreads();
        short8 af[4], bf[4];
#pragma unroll
        for (int t = 0; t < 4; t++) {
            af[t] = *(const short8*)(sA + (wm * 64 + t * 16 + l15) * 32 + quad * 8);
            bf[t] = *(const short8*)(sB + (wn * 64 + t * 16 + l15) * 32 + quad * 8);
        }
#pragma unroll
        for (int tm = 0; tm < 4; tm++)
#pragma unroll
            for (int tn = 0; tn < 4; tn++) acc[tm][tn] = mfma16(af[tm], bf[tn], acc[tm][tn]);
    }

    __syncthreads();  // staging reads done; pool becomes sOut

    const int b = m0 >> 11, nnb = m0 & 2047;
    const bool isV = (n0 >= 2048);
    if (!isV) {
        // q scale folds softmax 1/8 and log2(e):  0.125 * 1.4426950408889634
        const float qs = (n0 < 1024) ? 0.18033688011112042f : 1.0f;
#pragma unroll
        for (int tn = 0; tn < 4; tn++) {
            const int d = tn * 16 + l15;
            const int colL = wn * 64 + tn * 16 + l15;
            const float inv = exp2f((float)(d >> 1) * -0.4152410118609203f);
#pragma unroll
            for (int tm = 0; tm < 4; tm++) {
                const int rowL = wm * 64 + tm * 16 + quad * 4;
#pragma unroll
                for (int i = 0; i < 4; i++) {
                    float v = acc[tm][tn][i];
                    float pv = __shfl_xor(v, 1);  // (even,odd) column pair partner
                    float ang = (float)(nnb + rowL + i) * inv;
                    float sn = __sinf(ang), cs = __cosf(ang);
                    float r = (d & 1) ? (pv * sn + v * cs) : (v * cs - pv * sn);
                    sOut[(rowL + i) * 136 + colL] = f2h(r * qs);
                }
            }
        }
        __syncthreads();
        short* dst0 = (n0 < 1024) ? Qd : Kd;
        const int hbase = (n0 & 1023) >> 6;
#pragma unroll
        for (int it = 0; it < 8; ++it) {
            int c = it * 256 + tid;
            int r = c >> 4, cg = (c & 15) * 8;
            int h = hbase + (cg >> 6), d = cg & 63;
            *(short8*)(dst0 + ((size_t)((b * 16 + h) * 2048 + nnb + r)) * 64 + d) =
                *(const short8*)(sOut + r * 136 + cg);
        }
    } else {
#pragma unroll
        for (int tn = 0; tn < 4; tn++) {
            const int colL = wn * 64 + tn * 16 + l15;
#pragma unroll
            for (int tm = 0; tm < 4; tm++) {
                const int rowL = wm * 64 + tm * 16 + quad * 4;
#pragma unroll
                for (int i = 0; i < 4; i++)
                    sOut[colL * 136 + rowL + i] = f2h(acc[tm][tn][i]);  // transposed tile
            }
        }
        __syncthreads();
        const int hbase = (n0 & 1023) >> 6;
#pragma unroll
        for (int it = 0; it < 8; ++it) {
            int c = it * 256 + tid;
            int ci = c >> 4, rg = (c & 15) * 8;
            int h = hbase + (ci >> 6), d = ci & 63;
            *(short8*)(VTb + ((size_t)((b * 16 + h) * 64 + d)) * 2048 + nnb + rg) =
                *(const short8*)(sOut + ci * 136 + rg);
        }
    }
}

// ---------------------------------------------------------------- out-proj GEMM (plain fp16)
__global__ __launch_bounds__(256, 2) void gemm_out(const short* __restrict__ A,
                                                   const short* __restrict__ BT,
                                                   float* __restrict__ Fout,
                                                   const float* __restrict__ bias) {
    __shared__ __align__(16) short sA[128 * 32];
    __shared__ __align__(16) short sB[128 * 32];
    const int tid = threadIdx.x;
    const int w = tid >> 6, lane = tid & 63, quad = lane >> 4, l15 = lane & 15;
    const int wm = w >> 1, wn = w & 1;
    const int m0 = blockIdx.y * 128, n0 = blockIdx.x * 128;

    floatx4 acc[4][4];
#pragma unroll
    for (int i = 0; i < 4; i++)
#pragma unroll
        for (int j = 0; j < 4; j++) acc[i][j] = (floatx4){0.f, 0.f, 0.f, 0.f};

    for (int k0 = 0; k0 < 1024; k0 += 32) {
        __syncthreads();
#pragma unroll
        for (int i = 0; i < 2; ++i) {
            int c = i * 256 + tid;
            int r = c >> 2, kc = (c & 3) << 3;
            async16(A + (size_t)(m0 + r) * 1024 + k0 + kc, (char*)sA + c * 16);
            async16(BT + (size_t)(n0 + r) * 1024 + k0 + kc, (char*)sB + c * 16);
        }
        __syncthreads();
        short8 af[4], bf[4];
#pragma unroll
        for (int t = 0; t < 4; t++) af[t] = *(const short8*)(sA + (wm * 64 + t * 16 + l15) * 32 + quad * 8);
#pragma unroll
        for (int t = 0; t < 4; t++) bf[t] = *(const short8*)(sB + (wn * 64 + t * 16 + l15) * 32 + quad * 8);
#pragma unroll
        for (int tm = 0; tm < 4; tm++)
#pragma unroll
            for (int tn = 0; tn < 4; tn++) acc[tm][tn] = mfma16(af[tm], bf[tn], acc[tm][tn]);
    }

#pragma unroll
    for (int tn = 0; tn < 4; tn++) {
        const int col = n0 + wn * 64 + tn * 16 + l15;
        const float bb = bias[col];
#pragma unroll
        for (int tm = 0; tm < 4; tm++) {
            const int row0 = m0 + wm * 64 + tm * 16 + quad * 4;
#pragma unroll
            for (int i = 0; i < 4; i++) Fout[(size_t)(row0 + i) * 1024 + col] = acc[tm][tn][i] + bb;
        }
    }
}

// ---------------------------------------------------------------- attention (flash, fp16)
// Q (roped, pre-scaled by 0.125*log2e) [bh][n][64], K (roped) [bh][n][64], VT [bh][64][n]
// out [b][n][h*64+d] fp16.  Q-tile 128 (32/wave), KV-tile 128.
// S^T = K*Q^T orientation -> packed b64 P stores; no-max softmax p=exp2(s);
// row-sums l via ones-MFMA; sP aliases sK (z parked in regs across barrier).
__global__ __launch_bounds__(256, 2) void attn_kernel(const short* __restrict__ Qg,
                                                      const short* __restrict__ Kg,
                                                      const short* __restrict__ VTg,
                                                      short* __restrict__ Og) {
    __shared__ __align__(16) short pool[25344];  // 50688 B
    short* sVT = pool;          // [64][132]
    short* sK = pool + 8448;    // [128][72]
    short* sP = pool + 8448;    // [128][132], alias over sK + tail (post-QK)

    const int tid = threadIdx.x;
    const int w = tid >> 6, lane = tid & 63, quad = lane >> 4, l15 = lane & 15;
    const int qt = blockIdx.x, bh = blockIdx.y;

    const short* Qp = Qg + (size_t)(bh * 2048 + qt * 128) * 64;
    const short* Kp = Kg + (size_t)bh * 2048 * 64;
    const short* Vp = VTg + (size_t)bh * 64 * 2048;

    short8 aq[2][2];
#pragma unroll
    for (int tq = 0; tq < 2; tq++)
#pragma unroll
        for (int kh = 0; kh < 2; kh++)
            aq[tq][kh] = *(const short8*)(Qp + (w * 32 + tq * 16 + l15) * 64 + kh * 32 + quad * 8);

    short8 ones;
#pragma unroll
    for (int j = 0; j < 8; j++) ones[j] = 0x3C00;  // 1.0h

    floatx4 o4[4][2], ol[2];
#pragma unroll
    for (int i = 0; i < 4; i++)
#pragma unroll
        for (int j = 0; j < 2; j++) o4[i][j] = (floatx4){0.f, 0.f, 0.f, 0.f};
    ol[0] = (floatx4){0.f, 0.f, 0.f, 0.f};
    ol[1] = (floatx4){0.f, 0.f, 0.f, 0.f};

    for (int kt = 0; kt < 16; ++kt) {
        const int n0 = kt * 128;
        __syncthreads();  // all reads of prior sVT/sP done before restaging
#pragma unroll
        for (int it = 0; it < 4; ++it) {
            {
                int r = it * 32 + (tid >> 3), c8 = (tid & 7) << 3;
                *(short8*)(sK + r * 72 + c8) = *(const short8*)(Kp + (size_t)(n0 + r) * 64 + c8);
            }
            {
                int d = it * 16 + (tid >> 4), c16 = (tid & 15) << 3;
                *(short8*)(sVT + d * 132 + c16) = *(const short8*)(Vp + (size_t)d * 2048 + n0 + c16);
            }
        }
        __syncthreads();

        // S^T = K * Q^T : C rows = n (quad*4+i), col = q (l15); z parked in regs
        floatx4 z[2][8];
#pragma unroll
        for (int tn = 0; tn < 8; tn++) {
            short8 kf0 = *(const short8*)(sK + (tn * 16 + l15) * 72 + quad * 8);
            short8 kf1 = *(const short8*)(sK + (tn * 16 + l15) * 72 + 32 + quad * 8);
#pragma unroll
            for (int tq = 0; tq < 2; tq++) {
                floatx4 zz = (floatx4){0.f, 0.f, 0.f, 0.f};
                zz = mfma16(kf0, aq[tq][0], zz);
                zz = mfma16(kf1, aq[tq][1], zz);
                z[tq][tn] = zz;
            }
        }
        __syncthreads();  // all sK reads done before sP overwrites it

        // P store: p = exp2(z), packed b64 at sP[q][n] (4 consecutive n per lane)
#pragma unroll
        for (int tq = 0; tq < 2; tq++) {
            const int qrow = w * 32 + tq * 16 + l15;
#pragma unroll
            for (int tn = 0; tn < 8; tn++) {
                int2 pk;
                pk.x = pk2(exp2f(z[tq][tn][0]), exp2f(z[tq][tn][1]));
                pk.y = pk2(exp2f(z[tq][tn][2]), exp2f(z[tq][tn][3]));
                *(int2*)(sP + qrow * 132 + tn * 16 + quad * 4) = pk;
            }
        }
        __syncthreads();  // P visible before PV reads

        // PV: O^T += V^T * P^T ; l via ones fragment
#pragma unroll
        for (int nc = 0; nc < 4; nc++) {
            short8 pa[4];
#pragma unroll
            for (int dt = 0; dt < 4; dt++)
                pa[dt] = *(const short8*)(sVT + (dt * 16 + l15) * 132 + nc * 32 + quad * 8);
            short8 pb[2];
#pragma unroll
            for (int tq = 0; tq < 2; tq++)
                pb[tq] = *(const short8*)(sP + (w * 32 + tq * 16 + l15) * 132 + nc * 32 + quad * 8);
#pragma unroll
            for (int dt = 0; dt < 4; dt++)
#pragma unroll
                for (int tq = 0; tq < 2; tq++) o4[dt][tq] = mfma16(pa[dt], pb[tq], o4[dt][tq]);
#pragma unroll
            for (int tq = 0; tq < 2; tq++) ol[tq] = mfma16(ones, pb[tq], ol[tq]);
        }
    }

    float linv[2];
#pragma unroll
    for (int tq = 0; tq < 2; tq++) linv[tq] = 1.0f / ol[tq][0];  // all C rows equal l[q]

    __syncthreads();  // last PV reads done; reuse pool as out-stage [128][72]
    short* sOut = pool + 8448;
#pragma unroll
    for (int dt = 0; dt < 4; dt++)
#pragma unroll
        for (int tq = 0; tq < 2; tq++) {
            int2 pk;
            pk.x = pk2(o4[dt][tq][0] * linv[tq], o4[dt][tq][1] * linv[tq]);
            pk.y = pk2(o4[dt][tq][2] * linv[tq], o4[dt][tq][3] * linv[tq]);
            *(int2*)(sOut + (w * 32 + tq * 16 + l15) * 72 + dt * 16 + quad * 4) = pk;
        }
    __syncthreads();
    const int b = bh >> 4, h = bh & 15;
#pragma unroll
    for (int it = 0; it < 4; ++it) {
        int c = it * 256 + tid;
        int r = c >> 3, dg = (c & 7) * 8;
        *(short8*)(Og + (size_t)(b * 2048 + qt * 128 + r) * 1024 + h * 64 + dg) =
            *(const short8*)(sOut + r * 72 + dg);
    }
}

// ---------------------------------------------------------------- launch
extern "C" void kernel_launch(void* const* d_in, const int* in_sizes, int n_in, void* d_out,
                              int out_size, void* d_ws, size_t ws_size, hipStream_t stream) {
    const float* x = (const float*)d_in[0];
    const float* gamma = (const float*)d_in[1];
    const float* beta = (const float*)d_in[2];
    const float* w_qkv = (const float*)d_in[3];
    const float* w_out = (const float*)d_in[4];
    const float* b_out = (const float*)d_in[5];
    float* out = (float*)d_out;

    char* ws = (char*)d_ws;
    short* xh = (short*)ws;                   // [8192][1024] fp16; later reused as attn out
    short* wqkvT = (short*)(ws + 16777216);   // [3072][1024]
    short* woT = (short*)(ws + 23068672);     // [1024][1024]
    short* VTb = (short*)(ws + 25165824);     // [64][64][2048]
    // Q and K live in d_out (2 x 16.78 MB); final GEMM overwrites it.
    short* Qd = (short*)d_out;                // [64][2048][64] (roped, scaled)
    short* Kd = (short*)d_out + 8388608;      // [64][2048][64] (roped)

    ln_kernel<<<8192, 256, 0, stream>>>(x, gamma, beta, xh);
    tcast_h<<<dim3(96, 32), dim3(32, 8), 0, stream>>>(w_qkv, wqkvT, 1024, 3072);
    tcast_h<<<dim3(32, 32), dim3(32, 8), 0, stream>>>(w_out, woT, 1024, 1024);
    gemm_qkv<<<dim3(24, 64), 256, 34816, stream>>>(xh, wqkvT, Qd, Kd, VTb);
    attn_kernel<<<dim3(16, 64), 256, 0, stream>>>(Qd, Kd, VTb, xh);
    gemm_out<<<dim3(8, 64), 256, 0, stream>>>(xh, woT, out, b_out);
}